// Round 16
// baseline (95.223 us; speedup 1.0000x reference)
//
#include <hip/hip_runtime.h>
#include <math.h>

// LossLayer: dist[b,r] = ||W[b]-R[r]||2 ; pred = one_hot(argmax_r dist) ;
// loss = mean(1 + dist[b,y] - dist[b, top2-excluding-y-at-top1]), y=argmax(label[b])
//
// R16 (single-variable change on R13, the best total at 81.7us): explicit
// software pipeline on the W stream. R13 issued each group's 16 uniform W
// loads immediately before consuming them -- W is 8MB read once => HBM-miss
// latency (~900cyc) exposed per group, 16x per wave, only 2 waves/SIMD to
// cover. R15's readlane alternative regressed (VALU->SGPR->VALU hazard
// stalls), so: DOUBLE-BUFFERED NAMED register sets A/B (16 f4 each): issue
// W(g+1) before computing g; first-use wait is one compute-group + ds-phase
// deep (~1300cyc across 2 waves > 900cyc HBM). Group 0 hoisted ABOVE the
// barrier (staging hides it). Loop rolled x2 (A/B alternation), not fully
// unrolled (R10's full unroll crashed). +64 VGPR -> ~200, still 2 waves/SIMD.
// Rest R13-verbatim: merged transpose staging into stride-65-padded LDS,
// lane-consecutive conflict-free re reads, block 512 / JB=2 / grid 256,
// ONE barrier, fused loss reduction.
#define NB 4096
#define NR 64
#define JB 2            // b-rows per wave
#define WVS 8           // waves per block (512 threads)
#define BBB (JB * WVS)  // 16 b-rows per block; grid = 256

typedef float f4v __attribute__((ext_vector_type(4)));

__global__ __launch_bounds__(512) void fused_loss_kernel(
    const float* __restrict__ w,
    const float* __restrict__ re,
    const float* __restrict__ label,
    float* __restrict__ out,
    float* __restrict__ ws)
{
    __shared__ f4v rl[128 * 65];    // transposed+padded re: slot=d4*65+r, 130 KB
    __shared__ float terms[WVS];

    const int tid = threadIdx.x;
    const int wv  = tid >> 6;       // wave id 0..7
    const int r   = tid & 63;       // lane = relation 0..63
    const int b0  = blockIdx.x * BBB;
    const int b_0 = b0 + wv * JB;
    const int b_1 = b_0 + 1;

    // uniform W row pointers (readfirstlane -> scalar addr; broadcast data)
    const f4v *wr0, *wr1;
    {
        int u0 = __builtin_amdgcn_readfirstlane(b_0);
        int u1 = __builtin_amdgcn_readfirstlane(b_1);
        wr0 = (const f4v*)(w + (size_t)u0 * 512);
        wr1 = (const f4v*)(w + (size_t)u1 * 512);
    }

    // ---- hoisted label loads ----
    float lv_0 = label[(size_t)b_0 * 64 + r];
    float lv_1 = label[(size_t)b_1 * 64 + r];

    // named W double-buffer sets (16 f4 each)
    f4v a0,a1,a2,a3,a4,a5,a6,a7,a8,a9,a10,a11,a12,a13,a14,a15;
    f4v c0,c1,c2,c3,c4,c5,c6,c7,c8,c9,c10,c11,c12,c13,c14,c15;

#define LOADW_A(g) { const f4v* p0 = wr0 + (g)*8; const f4v* p1 = wr1 + (g)*8; \
    a0=p0[0]; a1=p0[1]; a2=p0[2]; a3=p0[3]; a4=p0[4]; a5=p0[5]; a6=p0[6]; a7=p0[7]; \
    a8=p1[0]; a9=p1[1]; a10=p1[2]; a11=p1[3]; a12=p1[4]; a13=p1[5]; a14=p1[6]; a15=p1[7]; }
#define LOADW_C(g) { const f4v* p0 = wr0 + (g)*8; const f4v* p1 = wr1 + (g)*8; \
    c0=p0[0]; c1=p0[1]; c2=p0[2]; c3=p0[3]; c4=p0[4]; c5=p0[5]; c6=p0[6]; c7=p0[7]; \
    c8=p1[0]; c9=p1[1]; c10=p1[2]; c11=p1[3]; c12=p1[4]; c13=p1[5]; c14=p1[6]; c15=p1[7]; }

    // ---- prefetch group 0 W loads (latency hidden under staging+barrier) ----
    LOADW_A(0)

    // ---- stage re row-major -> LDS transposed (one-time, R13-verbatim) ----
    const f4v* re4g = (const f4v*)re;
    #pragma unroll
    for (int i = 0; i < 16; i++) {
        int idx = i * 512 + tid;                 // row=idx>>7, d4=idx&127
        f4v v = re4g[idx];                       // coalesced; consumed at once
        rl[(idx & 127) * 65 + (idx >> 7)] = v;
    }

    f4v acc0 = {0.f, 0.f, 0.f, 0.f};
    f4v acc1 = {0.f, 0.f, 0.f, 0.f};

    __syncthreads();   // ONE drain: re resident+transposed; loop barrier-free

#define STEP(q0, q1, vv)                                                     \
        {                                                                    \
            f4v dxa = q0 - vv;  acc0 = dxa * dxa + acc0;                     \
            f4v dxb = q1 - vv;  acc1 = dxb * dxb + acc1;                     \
        }

    // hot loop: 8 iterations, 2 groups each (A then C). Per group:
    // issue next group's 16 W loads FIRST (vmcnt pipeline), then 8
    // lane-consecutive ds_read_b128 (conflict-free), then FMA on the
    // PREVIOUSLY-loaded W set (no wait on the just-issued loads).
    #pragma unroll 1
    for (int gg = 0; gg < 8; gg++) {
        const int ge = gg * 2;
        const int go = ge + 1;

        // -- even group: compute with A; prefetch odd group into C --
        LOADW_C(go)
        {
            const f4v* rp = &rl[ge * 8 * 65 + r];
            f4v v0 = rp[0*65], v1 = rp[1*65], v2 = rp[2*65], v3 = rp[3*65];
            f4v v4 = rp[4*65], v5 = rp[5*65], v6 = rp[6*65], v7 = rp[7*65];
            STEP(a0, a8,  v0) STEP(a1, a9,  v1) STEP(a2, a10, v2) STEP(a3, a11, v3)
            STEP(a4, a12, v4) STEP(a5, a13, v5) STEP(a6, a14, v6) STEP(a7, a15, v7)
        }

        // -- odd group: compute with C; prefetch next even group into A --
        if (gg < 7) LOADW_A(ge + 2)
        {
            const f4v* rp = &rl[go * 8 * 65 + r];
            f4v v0 = rp[0*65], v1 = rp[1*65], v2 = rp[2*65], v3 = rp[3*65];
            f4v v4 = rp[4*65], v5 = rp[5*65], v6 = rp[6*65], v7 = rp[7*65];
            STEP(c0, c8,  v0) STEP(c1, c9,  v1) STEP(c2, c10, v2) STEP(c3, c11, v3)
            STEP(c4, c12, v4) STEP(c5, c13, v5) STEP(c6, c14, v6) STEP(c7, c15, v7)
        }
    }
#undef STEP
#undef LOADW_A
#undef LOADW_C

    // ---- epilogue per j: top-2/argmax + label argmax + loss term ----
    float lsum = 0.0f;
    #pragma unroll
    for (int j = 0; j < JB; j++) {
        int b = (j == 0) ? b_0 : b_1;
        f4v accj = (j == 0) ? acc0 : acc1;
        float d = sqrtf((accj.x + accj.y) + (accj.z + accj.w));

        float m1 = d; int i1 = r; float m2 = -3.0e38f;
        #pragma unroll
        for (int mask = 1; mask <= 32; mask <<= 1) {
            float om1 = __shfl_xor(m1, mask, 64);
            int   oi1 = __shfl_xor(i1, mask, 64);
            float om2 = __shfl_xor(m2, mask, 64);
            bool ob1 = (om1 > m1) || (om1 == m1 && oi1 < i1);
            float w1 = ob1 ? om1 : m1;  int wi1 = ob1 ? oi1 : i1;
            float l1_ = ob1 ? m1 : om1;         // loser's top-1 (value only)
            float c2 = ob1 ? om2 : m2;          // winner's top-2 (value only)
            m1 = w1; i1 = wi1;
            m2 = (c2 > l1_) ? c2 : l1_;
        }

        float lv = (j == 0) ? lv_0 : lv_1; int ly = r;
        #pragma unroll
        for (int mask = 1; mask <= 32; mask <<= 1) {
            float ov = __shfl_xor(lv, mask, 64);
            int   oy = __shfl_xor(ly, mask, 64);
            if (ov > lv || (ov == lv && oy < ly)) { lv = ov; ly = oy; }
        }
        int y = ly;

        float plus  = __shfl(d, y, 64);       // dist[b][y]
        float minus = (i1 == y) ? m2 : m1;    // top-2 value if top-1 == y
        lsum += 1.0f + plus - minus;

        out[(size_t)b * 64 + r] = (i1 == r) ? 1.0f : 0.0f;   // pred one-hot
    }

    if (r == 0) terms[wv] = lsum;

    // ---- fused loss reduction: block partial -> device atomic -> last block
    __syncthreads();
    if (tid == 0) {
        float t = (((terms[0] + terms[1]) + (terms[2] + terms[3]))
                 + ((terms[4] + terms[5]) + (terms[6] + terms[7]))) * (1.0f / NB);
        atomicAdd(ws, t);                     // ws[0] = loss accumulator (zeroed)
        __threadfence();                      // order add before counter inc
        unsigned old = atomicAdd((unsigned*)(ws + 1), 1u);   // ws[1] = counter
        if (old == (unsigned)(gridDim.x - 1)) {
            float total = atomicAdd(ws, 0.0f);   // all 256 adds visible
            out[(size_t)NB * NR] = total;
        }
    }
}

extern "C" void kernel_launch(void* const* d_in, const int* in_sizes, int n_in,
                              void* d_out, int out_size, void* d_ws, size_t ws_size,
                              hipStream_t stream) {
    const float* w   = (const float*)d_in[0];   // [4096,512]
    const float* re  = (const float*)d_in[1];   // [64,512]
    const float* lab = (const float*)d_in[2];   // [4096,64]
    float* out = (float*)d_out;                 // pred [4096,64] ++ loss [1]
    float* ws  = (float*)d_ws;                  // [0]=loss acc, [1]=done counter

    hipMemsetAsync(ws, 0, 8, stream);           // zero acc + counter (graph-safe)
    fused_loss_kernel<<<NB / BBB, 512, 0, stream>>>(w, re, lab, out, ws);
}

// Round 17
// 86.037 us; speedup vs baseline: 1.1068x; 1.1068x over previous
//
#include <hip/hip_runtime.h>
#include <math.h>

// LossLayer: dist[b,r] = ||W[b]-R[r]||2 ; pred = one_hot(argmax_r dist) ;
// loss = mean(1 + dist[b,y] - dist[b, top2-excluding-y-at-top1]), y=argmax(label[b])
//
// R17: occupancy is THE variable: 1 wave/SIMD ~ 49us (R14,R16), 2 waves/SIMD
// ~ 30-35us (R12,R13), VALU issue only ~8us (R14 calib). Untried cell:
// >=4 waves/SIMD with R13's proven hot-loop shape. Halve LDS via d-split:
// LDS = half of re (64 d4, transposed, stride-65 pad, 66.5 KB) -> grid 512,
// block 512, JB=1 row/wave -> 2 blocks/CU = 4 waves/SIMD. Two phases
// (stage half, barrier, compute 8 groups) x2 -- 3 barriers total; with 2
// blocks/CU a barrier in one block doesn't idle the CU. Per-group shape
// R13-verbatim: 8 uniform W vmcnt loads + 8 lane-consecutive ds_read_b128 +
// packed-f4 FMA. JB=1 keeps ~100 VGPR <= 128 (R16's VGPR>256 -> 1 wave/SIMD
// was the regression cause; R2's launch_bounds cap caused spills -- so no
// cap, just few live registers).
#define NB 4096
#define NR 64
#define WVS 8           // waves per block (512 threads), JB=1 row per wave
#define BBB WVS         // 8 b-rows per block; grid = 512

typedef float f4v __attribute__((ext_vector_type(4)));

__global__ __launch_bounds__(512) void fused_loss_kernel(
    const float* __restrict__ w,
    const float* __restrict__ re,
    const float* __restrict__ label,
    float* __restrict__ out,
    float* __restrict__ ws)
{
    __shared__ f4v rl[64 * 65];     // HALF of re, transposed+padded: 66560 B
    __shared__ float terms[WVS];

    const int tid = threadIdx.x;
    const int wv  = tid >> 6;       // wave id 0..7
    const int r   = tid & 63;       // lane = relation 0..63
    const int b   = blockIdx.x * BBB + wv;   // this wave's b-row

    // uniform W row pointer (readfirstlane -> scalar addr; broadcast data)
    const f4v* wr;
    {
        int u = __builtin_amdgcn_readfirstlane(b);
        wr = (const f4v*)(w + (size_t)u * 512);
    }

    // hoisted label load
    float lv = label[(size_t)b * 64 + r];

    const f4v* re4g = (const f4v*)re;
    f4v acc = {0.f, 0.f, 0.f, 0.f};

    #pragma unroll 1
    for (int half = 0; half < 2; half++) {
        // ---- stage d4 half*64..+63 transposed: wave i stages row k>>6,
        // lanes cover 64 consecutive d4 (1 KB contiguous global run) ----
        #pragma unroll
        for (int i = 0; i < 8; i++) {
            int k   = i * 512 + tid;            // 4096 f4 per half
            int d4l = k & 63;                   // local d4 (lane-consecutive)
            int rr  = k >> 6;                   // relation row (wave-uniform)
            f4v v = re4g[rr * 128 + half * 64 + d4l];   // coalesced
            rl[d4l * 65 + rr] = v;              // transposed store
        }
        __syncthreads();                        // half staged

        // ---- compute 8 groups of 8 d4 (R13-shape) ----
        #pragma unroll 1
        for (int g = 0; g < 8; g++) {
            const int gb = g * 8;
            const f4v* p = wr + half * 64 + gb;  // uniform vmcnt loads
            f4v q0 = p[0], q1 = p[1], q2 = p[2], q3 = p[3];
            f4v q4 = p[4], q5 = p[5], q6 = p[6], q7 = p[7];

            const f4v* rp = &rl[gb * 65 + r];    // lane-consecutive 16 B
            f4v v0 = rp[0*65], v1 = rp[1*65], v2 = rp[2*65], v3 = rp[3*65];
            f4v v4 = rp[4*65], v5 = rp[5*65], v6 = rp[6*65], v7 = rp[7*65];

#define STEP(q, vv) { f4v dx = q - vv;  acc = dx * dx + acc; }
            STEP(q0, v0) STEP(q1, v1) STEP(q2, v2) STEP(q3, v3)
            STEP(q4, v4) STEP(q5, v5) STEP(q6, v6) STEP(q7, v7)
#undef STEP
        }
        if (half == 0) __syncthreads();         // all reads done before restage
    }

    // ---- epilogue: top-2/argmax + label argmax + loss term (JB=1) ----
    float d = sqrtf((acc.x + acc.y) + (acc.z + acc.w));

    float m1 = d; int i1 = r; float m2 = -3.0e38f;
    #pragma unroll
    for (int mask = 1; mask <= 32; mask <<= 1) {
        float om1 = __shfl_xor(m1, mask, 64);
        int   oi1 = __shfl_xor(i1, mask, 64);
        float om2 = __shfl_xor(m2, mask, 64);
        bool ob1 = (om1 > m1) || (om1 == m1 && oi1 < i1);
        float w1 = ob1 ? om1 : m1;  int wi1 = ob1 ? oi1 : i1;
        float l1_ = ob1 ? m1 : om1;             // loser's top-1 (value only)
        float c2 = ob1 ? om2 : m2;              // winner's top-2 (value only)
        m1 = w1; i1 = wi1;
        m2 = (c2 > l1_) ? c2 : l1_;
    }

    int ly = r;
    #pragma unroll
    for (int mask = 1; mask <= 32; mask <<= 1) {
        float ov = __shfl_xor(lv, mask, 64);
        int   oy = __shfl_xor(ly, mask, 64);
        if (ov > lv || (ov == lv && oy < ly)) { lv = ov; ly = oy; }
    }
    int y = ly;

    float plus  = __shfl(d, y, 64);           // dist[b][y]
    float minus = (i1 == y) ? m2 : m1;        // top-2 value if top-1 == y
    if (r == 0) terms[wv] = 1.0f + plus - minus;

    out[(size_t)b * 64 + r] = (i1 == r) ? 1.0f : 0.0f;   // pred one-hot

    // ---- fused loss reduction: block partial -> device atomic -> last block
    __syncthreads();
    if (tid == 0) {
        float t = (((terms[0] + terms[1]) + (terms[2] + terms[3]))
                 + ((terms[4] + terms[5]) + (terms[6] + terms[7]))) * (1.0f / NB);
        atomicAdd(ws, t);                     // ws[0] = loss accumulator (zeroed)
        __threadfence();                      // order add before counter inc
        unsigned old = atomicAdd((unsigned*)(ws + 1), 1u);   // ws[1] = counter
        if (old == (unsigned)(gridDim.x - 1)) {
            float total = atomicAdd(ws, 0.0f);   // all 512 adds visible
            out[(size_t)NB * NR] = total;
        }
    }
}

extern "C" void kernel_launch(void* const* d_in, const int* in_sizes, int n_in,
                              void* d_out, int out_size, void* d_ws, size_t ws_size,
                              hipStream_t stream) {
    const float* w   = (const float*)d_in[0];   // [4096,512]
    const float* re  = (const float*)d_in[1];   // [64,512]
    const float* lab = (const float*)d_in[2];   // [4096,64]
    float* out = (float*)d_out;                 // pred [4096,64] ++ loss [1]
    float* ws  = (float*)d_ws;                  // [0]=loss acc, [1]=done counter

    hipMemsetAsync(ws, 0, 8, stream);           // zero acc + counter (graph-safe)
    fused_loss_kernel<<<NB / BBB, 512, 0, stream>>>(w, re, lab, out, ws);
}

// Round 18
// 81.777 us; speedup vs baseline: 1.1644x; 1.0521x over previous
//
#include <hip/hip_runtime.h>
#include <math.h>

// LossLayer: dist[b,r] = ||W[b]-R[r]||2 ; pred = one_hot(argmax_r dist) ;
// loss = mean(1 + dist[b,y] - dist[b, top2-excluding-y-at-top1]), y=argmax(label[b])
//
// R18 = R13 VERBATIM (measured best: 81.7 us total). Design-matrix summary
// of rounds 1-17: 1 wave/SIMD ~49us (R14,R16), 2 waves/SIMD ~30us (R12,R13),
// 4 waves/SIMD with halved JB ~36us (R17: ds_read amortization loss beats
// occupancy gain). W-path probes: s_load serializes on lgkm (R7), readlane
// stalls on VALU->SGPR hazard (R15), register double-buffer tips the VGPR
// cliff (R16). Fixed harness floor ~50us (41us = 268MB ws re-poison fill AT
// the HBM roofline + restores/gaps). R13's structure: merged re transpose
// into stride-65-padded LDS (130 KB, writes one-time <=8-way, hot reads
// lane-consecutive conflict-free), uniform-address W vmcnt loads batched
// 16/group, packed-f4v math, block 512 / JB=2 / grid 256, ONE barrier,
// fused loss reduction via device atomic + completion counter.
#define NB 4096
#define NR 64
#define JB 2            // b-rows per wave
#define WVS 8           // waves per block (512 threads)
#define BBB (JB * WVS)  // 16 b-rows per block; grid = 256

typedef float f4v __attribute__((ext_vector_type(4)));

__global__ __launch_bounds__(512) void fused_loss_kernel(
    const float* __restrict__ w,
    const float* __restrict__ re,
    const float* __restrict__ label,
    float* __restrict__ out,
    float* __restrict__ ws)
{
    __shared__ f4v rl[128 * 65];    // transposed+padded re: slot=d4*65+r, 130 KB
    __shared__ float terms[WVS];

    const int tid = threadIdx.x;
    const int wv  = tid >> 6;       // wave id 0..7
    const int r   = tid & 63;       // lane = relation 0..63
    const int b0  = blockIdx.x * BBB;

    // ---- stage re row-major -> LDS transposed (one-time) ----
    const f4v* re4g = (const f4v*)re;
    #pragma unroll
    for (int i = 0; i < 16; i++) {
        int idx = i * 512 + tid;                 // row=idx>>7, d4=idx&127
        f4v v = re4g[idx];                       // coalesced; consumed at once
        rl[(idx & 127) * 65 + (idx >> 7)] = v;
    }

    // ---- hoisted label loads (latency hidden under staging) ----
    const int b_0 = b0 + wv * JB;
    const int b_1 = b_0 + 1;
    float lv_0 = label[(size_t)b_0 * 64 + r];
    float lv_1 = label[(size_t)b_1 * 64 + r];

    // uniform W row pointers (readfirstlane -> scalar addr; broadcast data)
    const f4v* wr0;
    const f4v* wr1;
    {
        int bu0 = __builtin_amdgcn_readfirstlane(b_0);
        int bu1 = __builtin_amdgcn_readfirstlane(b_1);
        wr0 = (const f4v*)(w + (size_t)bu0 * 512);
        wr1 = (const f4v*)(w + (size_t)bu1 * 512);
    }

    f4v acc0 = {0.f, 0.f, 0.f, 0.f};
    f4v acc1 = {0.f, 0.f, 0.f, 0.f};

    __syncthreads();   // ONE drain: re resident+transposed; loop barrier-free

    // hot loop: 16 groups of 8 d4. Per group: 16 uniform W vector loads
    // (vmcnt broadcast) + 8 lane-consecutive ds_read_b128 (conflict-free)
    // + packed-f32 FMA. unroll-4 gives the scheduler a hoisting window.
    #pragma unroll 4
    for (int g = 0; g < 16; g++) {
        const int gb = g * 8;

        f4v qa0 = wr0[gb+0], qa1 = wr0[gb+1], qa2 = wr0[gb+2], qa3 = wr0[gb+3];
        f4v qa4 = wr0[gb+4], qa5 = wr0[gb+5], qa6 = wr0[gb+6], qa7 = wr0[gb+7];
        f4v qb0 = wr1[gb+0], qb1 = wr1[gb+1], qb2 = wr1[gb+2], qb3 = wr1[gb+3];
        f4v qb4 = wr1[gb+4], qb5 = wr1[gb+5], qb6 = wr1[gb+6], qb7 = wr1[gb+7];

        const f4v* rp = &rl[gb * 65 + r];        // slot=(gb+k)*65+r
        f4v v0 = rp[0*65], v1 = rp[1*65], v2 = rp[2*65], v3 = rp[3*65];
        f4v v4 = rp[4*65], v5 = rp[5*65], v6 = rp[6*65], v7 = rp[7*65];

#define STEP(qa, qb, vv)                                                     \
        {                                                                    \
            f4v dxa = qa - vv;  acc0 = dxa * dxa + acc0;                     \
            f4v dxb = qb - vv;  acc1 = dxb * dxb + acc1;                     \
        }
        STEP(qa0, qb0, v0) STEP(qa1, qb1, v1) STEP(qa2, qb2, v2) STEP(qa3, qb3, v3)
        STEP(qa4, qb4, v4) STEP(qa5, qb5, v5) STEP(qa6, qb6, v6) STEP(qa7, qb7, v7)
#undef STEP
    }

    // ---- epilogue per j: top-2/argmax + label argmax + loss term ----
    float lsum = 0.0f;
    #pragma unroll
    for (int j = 0; j < JB; j++) {
        int b = (j == 0) ? b_0 : b_1;
        f4v accj = (j == 0) ? acc0 : acc1;
        float d = sqrtf((accj.x + accj.y) + (accj.z + accj.w));

        float m1 = d; int i1 = r; float m2 = -3.0e38f;
        #pragma unroll
        for (int mask = 1; mask <= 32; mask <<= 1) {
            float om1 = __shfl_xor(m1, mask, 64);
            int   oi1 = __shfl_xor(i1, mask, 64);
            float om2 = __shfl_xor(m2, mask, 64);
            bool ob1 = (om1 > m1) || (om1 == m1 && oi1 < i1);
            float w1 = ob1 ? om1 : m1;  int wi1 = ob1 ? oi1 : i1;
            float l1_ = ob1 ? m1 : om1;         // loser's top-1 (value only)
            float c2 = ob1 ? om2 : m2;          // winner's top-2 (value only)
            m1 = w1; i1 = wi1;
            m2 = (c2 > l1_) ? c2 : l1_;
        }

        float lv = (j == 0) ? lv_0 : lv_1; int ly = r;
        #pragma unroll
        for (int mask = 1; mask <= 32; mask <<= 1) {
            float ov = __shfl_xor(lv, mask, 64);
            int   oy = __shfl_xor(ly, mask, 64);
            if (ov > lv || (ov == lv && oy < ly)) { lv = ov; ly = oy; }
        }
        int y = ly;

        float plus  = __shfl(d, y, 64);       // dist[b][y]
        float minus = (i1 == y) ? m2 : m1;    // top-2 value if top-1 == y
        lsum += 1.0f + plus - minus;

        out[(size_t)b * 64 + r] = (i1 == r) ? 1.0f : 0.0f;   // pred one-hot
    }

    if (r == 0) terms[wv] = lsum;

    // ---- fused loss reduction: block partial -> device atomic -> last block
    __syncthreads();
    if (tid == 0) {
        float t = (((terms[0] + terms[1]) + (terms[2] + terms[3]))
                 + ((terms[4] + terms[5]) + (terms[6] + terms[7]))) * (1.0f / NB);
        atomicAdd(ws, t);                     // ws[0] = loss accumulator (zeroed)
        __threadfence();                      // order add before counter inc
        unsigned old = atomicAdd((unsigned*)(ws + 1), 1u);   // ws[1] = counter
        if (old == (unsigned)(gridDim.x - 1)) {
            float total = atomicAdd(ws, 0.0f);   // all 256 adds visible
            out[(size_t)NB * NR] = total;
        }
    }
}

extern "C" void kernel_launch(void* const* d_in, const int* in_sizes, int n_in,
                              void* d_out, int out_size, void* d_ws, size_t ws_size,
                              hipStream_t stream) {
    const float* w   = (const float*)d_in[0];   // [4096,512]
    const float* re  = (const float*)d_in[1];   // [64,512]
    const float* lab = (const float*)d_in[2];   // [4096,64]
    float* out = (float*)d_out;                 // pred [4096,64] ++ loss [1]
    float* ws  = (float*)d_ws;                  // [0]=loss acc, [1]=done counter

    hipMemsetAsync(ws, 0, 8, stream);           // zero acc + counter (graph-safe)
    fused_loss_kernel<<<NB / BBB, 512, 0, stream>>>(w, re, lab, out, ws);
}